// Round 2
// baseline (1050.324 us; speedup 1.0000x reference)
//
#include <hip/hip_runtime.h>

// NMS over 64 binary 3D masks (B=1, N=64, V=256*256*32 = 2,097,152 fp32 0/1 values).
// Strategy:
//   K1 (fused, memory-bound): bitpack chunks of all 64 rows via __ballot into LDS,
//       pairwise AND+popcount with 4x4 register tiling, atomicAdd partial counts
//       into upper-triangular inter[64][64] (uint32) in d_ws.  512 MiB read once.
//   K2 (1 wave): exact sequential NMS suppression via ballot/ffs, pure integer math
//       (iou > 0.5  <=>  2*inter > union, exact for counts < 2^22).
// Output dtype: harness reads d_out as int32 (reference returns bool) -> write int 0/1.

#define NROWS   64
#define ROWLEN  2097152                // floats per instance
#define WPB     32                     // uint64 bit-words per row per block
#define FPB     (WPB * 64)             // 2048 floats per row per block
#define NBLKS   (ROWLEN / FPB)         // 1024 blocks

__global__ __launch_bounds__(256, 4) void nms_pack_pairs(const float* __restrict__ mask,
                                                         unsigned int* __restrict__ inter) {
    __shared__ unsigned long long bits[NROWS][WPB];   // 16 KiB
    const int tid  = threadIdx.x;
    const int wv   = tid >> 6;          // wave 0..3
    const int lane = tid & 63;
    const size_t colbase = (size_t)blockIdx.x * FPB;

    // ---- stage: bitpack 2048 floats of each of the 64 rows into LDS ----
    for (int r = 0; r < NROWS; ++r) {
        const float* rowp = mask + (size_t)r * ROWLEN + colbase + wv * 512;
        const float4 fa = ((const float4*)rowp)[lane];          // floats [wv*512 + lane*4 .. +4)
        const float4 fb = ((const float4*)(rowp + 256))[lane];  // next 256-float group
        // ballot of component c over 64 lanes -> one 64-bit word (bit permutation is
        // identical for every row, so AND+popcount counts are exact)
        unsigned long long b0 = __ballot(fa.x > 0.5f);
        unsigned long long b1 = __ballot(fa.y > 0.5f);
        unsigned long long b2 = __ballot(fa.z > 0.5f);
        unsigned long long b3 = __ballot(fa.w > 0.5f);
        unsigned long long b4 = __ballot(fb.x > 0.5f);
        unsigned long long b5 = __ballot(fb.y > 0.5f);
        unsigned long long b6 = __ballot(fb.z > 0.5f);
        unsigned long long b7 = __ballot(fb.w > 0.5f);
        if (lane == 0) {
            const int wb = wv * 8;
            bits[r][wb + 0] = b0; bits[r][wb + 1] = b1;
            bits[r][wb + 2] = b2; bits[r][wb + 3] = b3;
            bits[r][wb + 4] = b4; bits[r][wb + 5] = b5;
            bits[r][wb + 6] = b6; bits[r][wb + 7] = b7;
        }
    }
    __syncthreads();

    // ---- pairwise popcount: 136 upper-tri 4x4-row tiles x 2 word-halves = 272 items ----
    for (int item = tid; item < 272; item += 256) {
        const int tile = item >> 1;
        const int h    = item & 1;
        int rem = tile, gi = 0;
        while (rem >= 16 - gi) { rem -= 16 - gi; ++gi; }
        const int gj = gi + rem;           // gi <= gj, 4-row groups

        unsigned int acc[4][4];
        #pragma unroll
        for (int a = 0; a < 4; ++a)
            #pragma unroll
            for (int b = 0; b < 4; ++b) acc[a][b] = 0u;

        #pragma unroll 4
        for (int step = 0; step < 16; ++step) {
            // lane-rotated word order -> ds_read_b64 at the 4-slot HW minimum, no hotspot
            const int w = h * 16 + ((step + lane) & 15);
            unsigned long long ai[4], bj[4];
            #pragma unroll
            for (int k = 0; k < 4; ++k) ai[k] = bits[gi * 4 + k][w];
            #pragma unroll
            for (int k = 0; k < 4; ++k) bj[k] = bits[gj * 4 + k][w];
            #pragma unroll
            for (int a = 0; a < 4; ++a)
                #pragma unroll
                for (int b = 0; b < 4; ++b)
                    acc[a][b] += (unsigned int)__popcll(ai[a] & bj[b]);
        }

        #pragma unroll
        for (int a = 0; a < 4; ++a) {
            #pragma unroll
            for (int b = 0; b < 4; ++b) {
                const int i = gi * 4 + a, j = gj * 4 + b;
                if (i <= j)  // upper triangle only (diag tile computes both orders; keep a<=b)
                    atomicAdd(&inter[i * 64 + j], acc[a][b]);
            }
        }
    }
}

// Exact replay of the reference's sequential suppression loop. One wave, lane j owns ind[j].
// Integer-exact: iou > 0.5  <=>  2*inter > union (counts < 2^22 are exact in f32, and the
// f32 divide's 2^-24 relative error cannot cross the >=2^-23 gap around 0.5).
__global__ __launch_bounds__(64) void nms_select(const unsigned int* __restrict__ inter,
                                                 int* __restrict__ out) {
    const int j = threadIdx.x;          // 64 lanes = one wave
    unsigned int cnt[64];
    #pragma unroll
    for (int i = 0; i < 64; ++i) {
        const int idx = (i <= j) ? (i * 64 + j) : (j * 64 + i);
        cnt[i] = inter[idx];
    }
    const unsigned int s = inter[j * 65];   // score[j] = diagonal popcount
    int ind = 1;

    #pragma unroll
    for (int i = 0; i < 64; ++i) {
        const int          ind_i = __shfl(ind, i);
        const unsigned int s_i   = (unsigned int)__shfl((int)s, i);
        const unsigned int ov    = cnt[i];
        const unsigned int uni   = s_i + s - ov;
        const bool hit = (2u * ov > uni);   // union==0 -> NaN in ref -> false; here 0>0 false too
        const unsigned long long A = __ballot(hit && (s > s_i));   // would clear ind[i]
        const unsigned long long B = __ballot(hit && (s_i > s));   // would clear ind[j] + break
        if (ind_i) {                        // 'if ind[i]==0: continue' (checked at row entry)
            const int jb = B ? (__ffsll((unsigned long long)B) - 1) : 64;  // first break j
            const unsigned long long low = (jb >= 64) ? ~0ULL : ((1ULL << jb) - 1ULL);
            if ((A & low) && j == i) ind = 0;       // A-events strictly before the break
            if (jb < 64 && j == jb) ind = 0;        // suppression at the break index
        }
    }
    out[j] = ind ? 1 : 0;                   // int32 output (reference returns bool)
}

extern "C" void kernel_launch(void* const* d_in, const int* in_sizes, int n_in,
                              void* d_out, int out_size, void* d_ws, size_t ws_size,
                              hipStream_t stream) {
    const float* mask   = (const float*)d_in[0];
    int*         out    = (int*)d_out;
    unsigned int* inter = (unsigned int*)d_ws;      // 64*64*4 = 16 KiB of scratch

    hipMemsetAsync(inter, 0, 64 * 64 * sizeof(unsigned int), stream);
    nms_pack_pairs<<<NBLKS, 256, 0, stream>>>(mask, inter);
    nms_select<<<1, 64, 0, stream>>>(inter, out);
}

// Round 3
// 750.106 us; speedup vs baseline: 1.4002x; 1.4002x over previous
//
#include <hip/hip_runtime.h>

// NMS over 64 binary 3D masks (B=1, N=64, V=2,097,152 fp32 0/1 values = 512 MiB).
// Atomic-free 4-kernel pipeline through d_ws (~19 MiB):
//   K1 pack:   512 MiB floats -> 16 MiB packed bits (pure streaming, the only heavy kernel)
//   K2 pairs:  LDS-tiled AND+popcount -> per-block pair partials (plain stores)
//   K2b:       reduce partials -> inter[2080] (upper-tri incl. diagonal)
//   K3 select: exact integer replay of the sequential suppression loop (verified round 2)
// Round-2 lesson: 4.45M device-scope atomics into 16 KiB serialized at the coherence
// point (~538 us, WRITE_SIZE 90 MB). This version has zero atomics.

#define NROWS          64
#define ROWLEN         2097152u                 // floats per instance
#define CHUNK_FLOATS   2048                     // one wave-iteration
#define NCHUNKS        65536                    // (64*2097152)/2048
#define WORDS_PER_ROW  65536                    // u32 words per row (2M bits / 32)
#define NPAIRS         2080                     // 64*65/2, includes diagonal (= scores)
#define K2_BLOCKS      256
#define WPC            256                      // u32 words per row per K2 block

// ---------- K1: bitpack. word[c*64+lane] bit (k*4+cc) = (float[c*2048 + k*256 + lane*4 + cc] != 0).
// Fixed position->bit permutation, identical for every row (row = 1024 chunks exactly),
// so AND+popcount of same-indexed words gives exact intersection counts.
__global__ __launch_bounds__(256) void nms_pack(const unsigned int* __restrict__ mask,
                                                unsigned int* __restrict__ packed) {
    const int lane = threadIdx.x & 63;
    const int wv   = threadIdx.x >> 6;
    const unsigned int wave_id = blockIdx.x * 4 + wv;        // 0..4095, 16 chunks each
    for (int it = 0; it < 16; ++it) {
        const size_t c = (size_t)wave_id * 16 + it;
        const unsigned int* base = mask + c * CHUNK_FLOATS + lane * 4;
        unsigned int word = 0u;
        #pragma unroll
        for (int k = 0; k < 8; ++k) {
            const uint4 v = *(const uint4*)(base + k * 256);  // coalesced 1 KiB per wave-load
            word |= (v.x != 0u ? 1u : 0u) << (k * 4 + 0);
            word |= (v.y != 0u ? 1u : 0u) << (k * 4 + 1);
            word |= (v.z != 0u ? 1u : 0u) << (k * 4 + 2);
            word |= (v.w != 0u ? 1u : 0u) << (k * 4 + 3);
        }
        packed[c * 64 + lane] = word;                         // coalesced store
    }
}

// ---------- K2: per-block column chunk (WPC words of every row) staged in 64 KiB LDS,
// all 2080 pair partial counts, plain stores to partial[p*K2_BLOCKS + b].
__global__ __launch_bounds__(256) void nms_pairs(const unsigned int* __restrict__ packed,
                                                 unsigned int* __restrict__ partial) {
    __shared__ unsigned int tile[NROWS * WPC];                // 64 KiB
    const int tid = threadIdx.x;
    const int b   = blockIdx.x;

    const uint4* p4 = (const uint4*)packed;
    uint4*       t4 = (uint4*)tile;
    for (int q = tid; q < NROWS * (WPC / 4); q += 256) {      // 4096 uint4, coalesced
        const int r  = q >> 6;                                // WPC/4 = 64 uint4 per row
        const int w4 = q & 63;
        t4[q] = p4[(size_t)r * (WORDS_PER_ROW / 4) + (size_t)b * (WPC / 4) + w4];
    }
    __syncthreads();

    const unsigned long long* t64 = (const unsigned long long*)tile;  // row stride 128
    const int lane = tid & 63;
    for (int p = tid; p < NPAIRS; p += 256) {
        int rem = p, i = 0;
        while (rem >= 64 - i) { rem -= 64 - i; ++i; }         // upper-tri decode, i<=j
        const int j = i + rem;
        const unsigned long long* ri = t64 + i * (WPC / 2);
        const unsigned long long* rj = t64 + j * (WPC / 2);
        unsigned int acc = 0;
        #pragma unroll 8
        for (int w = 0; w < WPC / 2; ++w) {
            const int m = (w + lane) & (WPC / 2 - 1);         // lane rotation spreads banks
            acc += (unsigned int)__popcll(ri[m] & rj[m]);
        }
        partial[(size_t)p * K2_BLOCKS + b] = acc;             // p-major for coalesced reduce
    }
}

// ---------- K2b: one wave per pair, sum 256 partials -> inter[p].
__global__ __launch_bounds__(256) void nms_reduce(const unsigned int* __restrict__ partial,
                                                  unsigned int* __restrict__ inter) {
    const int p    = blockIdx.x * 4 + (threadIdx.x >> 6);     // 520 blocks * 4 waves = 2080
    const int lane = threadIdx.x & 63;
    const uint4 v = ((const uint4*)partial)[(size_t)p * 64 + lane];  // coalesced 1 KiB
    unsigned int s = v.x + v.y + v.z + v.w;
    #pragma unroll
    for (int off = 32; off >= 1; off >>= 1) s += (unsigned int)__shfl_xor((int)s, off);
    if (lane == 0) inter[p] = s;
}

// ---------- K3: exact sequential suppression (integer-exact: iou>0.5 <=> 2*inter>union;
// counts < 2^22 are exact in f32 and the f32 divide cannot cross the >=2^-23 gap at 0.5).
__global__ __launch_bounds__(256) void nms_select(const unsigned int* __restrict__ inter,
                                                  int* __restrict__ out) {
    __shared__ unsigned int sI[NPAIRS];                       // 8.3 KiB
    const int tid = threadIdx.x;
    for (int p = tid; p < NPAIRS; p += 256) sI[p] = inter[p];
    __syncthreads();
    if (tid < 64) {
        const int j = tid;                                    // one wave, lane j owns ind[j]
        unsigned int cnt[64];
        #pragma unroll
        for (int i = 0; i < 64; ++i) {
            const int lo = i < j ? i : j, hi = i < j ? j : i;
            cnt[i] = sI[lo * 64 - lo * (lo - 1) / 2 + (hi - lo)];
        }
        const unsigned int s = cnt[j];                        // diagonal = score[j]
        int ind = 1;
        #pragma unroll
        for (int i = 0; i < 64; ++i) {
            const int          ind_i = __shfl(ind, i);
            const unsigned int s_i   = (unsigned int)__shfl((int)s, i);
            const unsigned int ov    = cnt[i];
            const unsigned int uni   = s_i + s - ov;
            const bool hit = (2u * ov > uni);                 // union==0 -> false (ref: NaN -> false)
            const unsigned long long A = __ballot(hit && (s > s_i));   // clears ind[i]
            const unsigned long long B = __ballot(hit && (s_i > s));   // clears ind[j] + break
            if (ind_i) {                                      // 'if ind[i]==0: continue'
                const int jb = B ? (__ffsll((unsigned long long)B) - 1) : 64;
                const unsigned long long low = (jb >= 64) ? ~0ULL : ((1ULL << jb) - 1ULL);
                if ((A & low) && j == i) ind = 0;             // A-events strictly before break
                if (jb < 64 && j == jb) ind = 0;              // suppression at break index
            }
        }
        out[j] = ind;                                         // int32 output (bool reference)
    }
}

extern "C" void kernel_launch(void* const* d_in, const int* in_sizes, int n_in,
                              void* d_out, int out_size, void* d_ws, size_t ws_size,
                              hipStream_t stream) {
    const unsigned int* mask = (const unsigned int*)d_in[0];  // floats are exactly 0.0f/1.0f
    int* out = (int*)d_out;

    // ws layout: packed 16 MiB | partial 2080*256*4 B | inter 2080*4 B   (~18.3 MiB total)
    unsigned int* packed  = (unsigned int*)d_ws;
    unsigned int* partial = packed + (size_t)NCHUNKS * 64;            // 4M u32
    unsigned int* inter   = partial + (size_t)NPAIRS * K2_BLOCKS;

    nms_pack  <<<1024, 256, 0, stream>>>(mask, packed);
    nms_pairs <<<K2_BLOCKS, 256, 0, stream>>>(packed, partial);
    nms_reduce<<<NPAIRS / 4, 256, 0, stream>>>(partial, inter);
    nms_select<<<1, 256, 0, stream>>>(inter, out);
}

// Round 4
// 715.918 us; speedup vs baseline: 1.4671x; 1.0478x over previous
//
#include <hip/hip_runtime.h>

// NMS over 64 binary 3D masks (B=1, N=64, V=2,097,152 fp32 0/1 values = 512 MiB).
// Round-4 structure: ONE fused streaming kernel (pack bits in LDS + all-pairs popcount,
// zero atomics, dense per-block partial stores), then a tiny reduce and the verified
// integer-exact sequential select.
//   - Round-2 lesson: 4.45M device-scope atomics into 16 KiB serialized (~538 us).
//   - Round-3 lesson: pack/pairs split costs an extra 16 MiB HBM round-trip + a
//     full-stream serialization; ~620 us of dur_us is harness d_ws-poison (2 GiB fill
//     @335 us) + d_in restore — outside kernel control. Controllable part ~130 us.

#define NROWS   64
#define ROWLEN  2097152u        // floats per instance
#define NB      1024            // fused-kernel blocks
#define CHUNK   2048            // floats per row per block (NB*CHUNK == ROWLEN)
#define NPAIRS  2080            // 64*65/2 upper-tri pairs incl. diagonal (= scores)
#define NPART   (NB * 2)        // partial slices: 2 word-halves per block

// ---------- K1: fused pack + all-pairs popcount ----------
// Pack: lane packs 32 floats (8 x uint4, stride 256 floats) into one u32; fixed
// position->bit permutation identical for every row, so AND+popcount is exact.
// Pairs: 136 upper-tri 4x4-row tiles x 2 16-word halves = 272 items over 256 threads;
// lane-rotated ds_read_b64 (0 bank conflicts measured in round 2).
__global__ __launch_bounds__(256, 4) void nms_fused(const unsigned int* __restrict__ mask,
                                                    unsigned int* __restrict__ partial) {
    __shared__ unsigned int bits32[NROWS][64];      // 16 KiB: 2048 bits per row
    const int tid  = threadIdx.x;
    const int lane = tid & 63;
    const int wv   = tid >> 6;
    const size_t colbase = (size_t)blockIdx.x * CHUNK;

    // ---- pack phase: wave wv packs rows 16*wv .. 16*wv+15 ----
    #pragma unroll 2
    for (int rr = 0; rr < 16; ++rr) {
        const int r = wv * 16 + rr;
        const unsigned int* base = mask + (size_t)r * ROWLEN + colbase + lane * 4;
        unsigned int word = 0u;
        #pragma unroll
        for (int k = 0; k < 8; ++k) {
            const uint4 v = *(const uint4*)(base + k * 256);   // coalesced 1 KiB/wave-load
            word |= (v.x != 0u ? 1u : 0u) << (k * 4 + 0);      // floats are exactly 0.0/1.0
            word |= (v.y != 0u ? 1u : 0u) << (k * 4 + 1);
            word |= (v.z != 0u ? 1u : 0u) << (k * 4 + 2);
            word |= (v.w != 0u ? 1u : 0u) << (k * 4 + 3);
        }
        bits32[r][lane] = word;                                 // coalesced ds_write_b32
    }
    __syncthreads();

    // ---- pairs phase ----
    for (int item = tid; item < 272; item += 256) {
        const int h = item & 1;
        int rem = item >> 1, gi = 0;
        while (rem >= 16 - gi) { rem -= 16 - gi; ++gi; }        // 4-row groups, gi <= gj
        const int gj = gi + rem;

        unsigned int acc[4][4];
        #pragma unroll
        for (int a = 0; a < 4; ++a)
            #pragma unroll
            for (int b = 0; b < 4; ++b) acc[a][b] = 0u;

        #pragma unroll 4
        for (int step = 0; step < 16; ++step) {
            const int w = h * 16 + ((step + lane) & 15);        // lane rotation spreads banks
            unsigned long long ai[4], bj[4];
            #pragma unroll
            for (int k = 0; k < 4; ++k)
                ai[k] = ((const unsigned long long*)bits32[gi * 4 + k])[w];
            #pragma unroll
            for (int k = 0; k < 4; ++k)
                bj[k] = ((const unsigned long long*)bits32[gj * 4 + k])[w];
            #pragma unroll
            for (int a = 0; a < 4; ++a)
                #pragma unroll
                for (int b = 0; b < 4; ++b)
                    acc[a][b] += (unsigned int)__popcll(ai[a] & bj[b]);
        }

        // dense store: slice (2*block + h) holds all 2080 pair partials contiguously
        const size_t sbase = ((size_t)blockIdx.x * 2 + h) * NPAIRS;
        #pragma unroll
        for (int a = 0; a < 4; ++a) {
            const int i = gi * 4 + a;
            #pragma unroll
            for (int b = 0; b < 4; ++b) {
                const int j = gj * 4 + b;
                if (i <= j)
                    partial[sbase + (i * 64 - i * (i - 1) / 2 + (j - i))] = acc[a][b];
            }
        }
    }
}

// ---------- K2: wave per pair, sum 2048 slice-partials -> inter[p] ----------
__global__ __launch_bounds__(256) void nms_reduce(const unsigned int* __restrict__ partial,
                                                  unsigned int* __restrict__ inter) {
    const int p    = blockIdx.x * 4 + (threadIdx.x >> 6);       // 520 blocks * 4 waves = 2080
    const int lane = threadIdx.x & 63;
    unsigned int s = 0;
    #pragma unroll 8
    for (int it = 0; it < NPART / 64; ++it)                     // 32 independent loads/lane
        s += partial[(size_t)(it * 64 + lane) * NPAIRS + p];
    #pragma unroll
    for (int off = 32; off >= 1; off >>= 1) s += (unsigned int)__shfl_xor((int)s, off);
    if (lane == 0) inter[p] = s;
}

// ---------- K3: exact sequential suppression (verified rounds 2-3) ----------
// Integer-exact: iou > 0.5 <=> 2*inter > union (counts < 2^22 exact in f32; the f32
// divide's 2^-24 rel. error cannot cross the >=2^-23 gap around 0.5).
__global__ __launch_bounds__(256) void nms_select(const unsigned int* __restrict__ inter,
                                                  int* __restrict__ out) {
    __shared__ unsigned int sI[NPAIRS];                         // 8.3 KiB
    const int tid = threadIdx.x;
    for (int p = tid; p < NPAIRS; p += 256) sI[p] = inter[p];
    __syncthreads();
    if (tid < 64) {
        const int j = tid;                                      // one wave, lane j owns ind[j]
        unsigned int cnt[64];
        #pragma unroll
        for (int i = 0; i < 64; ++i) {
            const int lo = i < j ? i : j, hi = i < j ? j : i;
            cnt[i] = sI[lo * 64 - lo * (lo - 1) / 2 + (hi - lo)];
        }
        const unsigned int s = cnt[j];                          // diagonal = score[j]
        int ind = 1;
        #pragma unroll
        for (int i = 0; i < 64; ++i) {
            const int          ind_i = __shfl(ind, i);
            const unsigned int s_i   = (unsigned int)__shfl((int)s, i);
            const unsigned int ov    = cnt[i];
            const unsigned int uni   = s_i + s - ov;
            const bool hit = (2u * ov > uni);                   // union==0 -> false (ref NaN -> false)
            const unsigned long long A = __ballot(hit && (s > s_i));   // clears ind[i]
            const unsigned long long B = __ballot(hit && (s_i > s));   // clears ind[j] + break
            if (ind_i) {                                        // 'if ind[i]==0: continue'
                const int jb = B ? (__ffsll((unsigned long long)B) - 1) : 64;
                const unsigned long long low = (jb >= 64) ? ~0ULL : ((1ULL << jb) - 1ULL);
                if ((A & low) && j == i) ind = 0;               // A-events strictly before break
                if (jb < 64 && j == jb) ind = 0;                // suppression at break index
            }
        }
        out[j] = ind;                                           // int32 output (bool reference)
    }
}

extern "C" void kernel_launch(void* const* d_in, const int* in_sizes, int n_in,
                              void* d_out, int out_size, void* d_ws, size_t ws_size,
                              hipStream_t stream) {
    const unsigned int* mask = (const unsigned int*)d_in[0];    // fp32 values are exactly 0/1
    int* out = (int*)d_out;

    // ws layout: partial [2048][2080] u32 (~17 MiB) | inter [2080] u32
    unsigned int* partial = (unsigned int*)d_ws;
    unsigned int* inter   = partial + (size_t)NPART * NPAIRS;

    nms_fused <<<NB, 256, 0, stream>>>(mask, partial);
    nms_reduce<<<NPAIRS / 4, 256, 0, stream>>>(partial, inter);
    nms_select<<<1, 256, 0, stream>>>(inter, out);
}